// Round 11
// baseline (76.156 us; speedup 1.0000x reference)
//
#include <hip/hip_runtime.h>
#include <hip/hip_bf16.h>
#include <stdint.h>

typedef float f32x2 __attribute__((ext_vector_type(2)));
typedef float f32x4 __attribute__((ext_vector_type(4)));
typedef short bf16x8 __attribute__((ext_vector_type(8)));
typedef unsigned int u32;

#define NTILES  8192
#define X_LIMIT (131072u * 310u - 2u)   // last safe f32x2 float-index into x

__device__ __forceinline__ f32x4 leaky4(f32x4 v) {
    return __builtin_elementwise_max(v, v * 0.01f);
}
__device__ __forceinline__ u32 pkbf(float a, float b) {
    union { __hip_bfloat162 h; u32 u; } c;
    c.h = __float22bfloat162_rn(make_float2(a, b));   // a -> low 16, b -> high 16
    return c.u;
}
__device__ __forceinline__ short bf1(float a) {
    union { __hip_bfloat16 h; short s; } c;
    c.h = __float2bfloat16(a);
    return c.s;
}

// One wave = 16 rows end-to-end. No barriers; LDS is per-wave scratch only.
__global__ __launch_bounds__(256) void gen_mlp_r11(
    const float* __restrict__ x, const float* __restrict__ data_t,
    const float* __restrict__ W1, const float* __restrict__ b1,
    const float* __restrict__ W2, const float* __restrict__ b2,
    const float* __restrict__ W3, const float* __restrict__ b3,
    float* __restrict__ out)
{
    __shared__ short a2s[4][16][32];   // per-wave h1(bf16) transpose scratch [row][k<=32]
    __shared__ f32x2 ccs[4][16];       // per-wave (c0,c1) per row

    const int tid  = threadIdx.x;
    const int w    = tid >> 6;          // wave in block
    const int lane = tid & 63;
    const int g    = lane >> 4;         // k-octet group / output row-quad
    const int j    = lane & 15;         // A-row / B-col / C-col
    const int jc   = (j < 10) ? j : 9;  // clamped W1-col (j>=10 lanes masked later)

    // zero the A2 scratch once; cols 10..31 stay zero forever (K-padding)
    *(f32x4*)((char*)&a2s[w][0][0] + lane * 16) = (f32x4){0.f, 0.f, 0.f, 0.f};

    // ---- one-time per-wave weight fragments (registers) ----
    bf16x8 w1f[10];                    // B-frag: W1[k=32s+8g+e][col=j], zero for k>=310 or j>=10
    #pragma unroll
    for (int s = 0; s < 10; ++s) {
        union { u32 d[4]; bf16x8 f; } u;
        #pragma unroll
        for (int e2 = 0; e2 < 4; ++e2) {
            const int k0 = 32 * s + 8 * g + 2 * e2;
            const float va = (k0     < 310 && j < 10) ? W1[k0 * 10 + jc]       : 0.f;
            const float vb = (k0 + 1 < 310 && j < 10) ? W1[(k0 + 1) * 10 + jc] : 0.f;
            u.d[e2] = pkbf(va, vb);
        }
        w1f[s] = u.f;
    }
    bf16x8 w2f[8];                     // B-frag per n-tile: W2[k=8g+e][16n+j], zero for k>=10
    #pragma unroll
    for (int n = 0; n < 8; ++n) {
        union { u32 d[4]; bf16x8 f; } u;
        #pragma unroll
        for (int e2 = 0; e2 < 4; ++e2) {
            const int k0 = 8 * g + 2 * e2;
            const float va = (k0     < 10) ? W2[k0 * 128 + 16 * n + j]       : 0.f;
            const float vb = (k0 + 1 < 10) ? W2[(k0 + 1) * 128 + 16 * n + j] : 0.f;
            u.d[e2] = pkbf(va, vb);
        }
        w2f[n] = u.f;
    }
    f32x2 w3v[8]; float b2v[8];
    #pragma unroll
    for (int n = 0; n < 8; ++n) {
        w3v[n] = *(const f32x2*)(W3 + (16 * n + j) * 2);
        b2v[n] = b2[16 * n + j];
    }
    const float b1v = b1[jc];
    const float b30 = b3[0], b31 = b3[1];

    const int gw = blockIdx.x * 4 + w;   // 0..2047; 4 contiguous tiles each

    #pragma unroll 1
    for (int t = gw * 4; t < gw * 4 + 4; ++t) {
        // ---- L1: x[16 rows x 310] @ W1 via 10 MFMAs; A direct from global ----
        const u32 xb0 = (u32)t * 4960u + (u32)j * 310u + 8u * (u32)g;  // float index
        f32x2 xp[2][4];
        #pragma unroll
        for (int i = 0; i < 4; ++i) xp[0][i] = *(const f32x2*)(x + xb0 + 2 * i);

        f32x4 acc = {0.f, 0.f, 0.f, 0.f};
        #pragma unroll
        for (int s = 0; s < 10; ++s) {
            if (s < 9) {   // prefetch next k-step (1 deep)
                const u32 o = xb0 + 32u * (s + 1);
                #pragma unroll
                for (int i = 0; i < 4; ++i) {
                    u32 oi = o + 2 * i;
                    if (s == 8 && oi > X_LIMIT) oi = X_LIMIT;  // tail clamp; W1=0 there
                    xp[(s + 1) & 1][i] = *(const f32x2*)(x + oi);
                }
            }
            union { u32 d[4]; bf16x8 f; } a;
            #pragma unroll
            for (int i = 0; i < 4; ++i)
                a.d[i] = pkbf(xp[s & 1][i].x, xp[s & 1][i].y);
            acc = __builtin_amdgcn_mfma_f32_16x16x32_bf16(a.f, w1f[s], acc, 0, 0, 0);
        }

        // ---- h1 = leaky(acc + b1), bf16, into per-wave transpose scratch ----
        const f32x4 h1 = leaky4(acc + b1v);     // lane: col j, rows 4g+r
        if (j < 10) {
            #pragma unroll
            for (int r = 0; r < 4; ++r)
                a2s[w][4 * g + r][j] = bf1(h1[r]);
        }

        // ---- data_t prefetch (covers L2/L3 latency) ----
        const f32x4* dt4 = (const f32x4*)data_t + (size_t)t * 400;
        f32x4 tv[6];
        #pragma unroll
        for (int q = 0; q < 6; ++q) tv[q] = dt4[lane + 64 * q];
        f32x4 tvL;
        if (lane < 16) tvL = dt4[384 + lane];

        // ---- L2 (8 MFMAs) fused with L3 partials ----
        const bf16x8 a2f = *(const bf16x8*)((const char*)&a2s[w][0][0] + j * 64 + g * 16);
        f32x4 c0a = {0.f, 0.f, 0.f, 0.f}, c1a = {0.f, 0.f, 0.f, 0.f};
        #pragma unroll
        for (int n = 0; n < 8; ++n) {
            const f32x4 z = {0.f, 0.f, 0.f, 0.f};
            f32x4 c2 = __builtin_amdgcn_mfma_f32_16x16x32_bf16(a2f, w2f[n], z, 0, 0, 0);
            f32x4 h2 = leaky4(c2 + b2v[n]);     // rows 4g+r, m = 16n+j
            c0a += h2 * w3v[n].x;
            c1a += h2 * w3v[n].y;
        }
        // reduce over the 16 j-lanes of this row-quad group
        #pragma unroll
        for (int m = 1; m <= 8; m <<= 1) {
            #pragma unroll
            for (int r = 0; r < 4; ++r) {
                c0a[r] += __shfl_xor(c0a[r], m, 64);
                c1a[r] += __shfl_xor(c1a[r], m, 64);
            }
        }
        const f32x4 cc0 = leaky4(c0a + b30);
        const f32x4 cc1 = leaky4(c1a + b31);
        if (j == 0) {
            #pragma unroll
            for (int r = 0; r < 4; ++r)
                ccs[w][4 * g + r] = (f32x2){cc0[r], cc1[r]};
        }

        // ---- epilogue: out = t*(c0 + c1*t), coalesced f32x4 over 16 rows ----
        f32x4* o4 = (f32x4*)out + (size_t)t * 400;
        #pragma unroll
        for (int q = 0; q < 6; ++q) {
            const int idx = lane + 64 * q;
            const f32x2 cc = ccs[w][idx / 25];
            o4[idx] = tv[q] * (tv[q] * cc.y + cc.x);
        }
        if (lane < 16) {
            const int idx = 384 + lane;
            const f32x2 cc = ccs[w][idx / 25];
            o4[idx] = tvL * (tvL * cc.y + cc.x);
        }
    }
}

extern "C" void kernel_launch(void* const* d_in, const int* in_sizes, int n_in,
                              void* d_out, int out_size, void* d_ws, size_t ws_size,
                              hipStream_t stream) {
    const float* x      = (const float*)d_in[0];
    const float* data_t = (const float*)d_in[1];
    const float* W1     = (const float*)d_in[2];
    const float* b1     = (const float*)d_in[3];
    const float* W2     = (const float*)d_in[4];
    const float* b2     = (const float*)d_in[5];
    const float* W3     = (const float*)d_in[6];
    const float* b3     = (const float*)d_in[7];
    float* out = (float*)d_out;

    // 512 blocks x 4 waves x 4 tiles x 16 rows = 131072 rows; no barriers anywhere
    gen_mlp_r11<<<512, 256, 0, stream>>>(x, data_t, W1, b1, W2, b2, W3, b3, out);
}